// Round 4
// baseline (752.851 us; speedup 1.0000x reference)
//
#include <hip/hip_runtime.h>
#include <hip/hip_bf16.h>

// Problem constants
constexpr int Bn  = 128;   // batch
constexpr int Ln  = 200;   // sentences
constexpr int D2n = 1024;  // 2*SH
constexpr int G3n = 1536;  // 3*EH
constexpr int Tn  = 3;
constexpr int Nn  = 512;   // A (attention dim) == d_proj cols
constexpr int Kn  = 1024;  // d_proj K

typedef unsigned short ushort;
typedef float f32x4 __attribute__((ext_vector_type(4)));
typedef __bf16 bf16x8 __attribute__((ext_vector_type(8)));

__device__ __forceinline__ ushort f2bf(float f) {   // RNE float->bf16
  unsigned u = __float_as_uint(f);
  unsigned r = (u + 0x7fffu + ((u >> 16) & 1u)) >> 16;
  return (ushort)r;
}
__device__ __forceinline__ float bf2f(ushort h) {
  return __uint_as_float(((unsigned)h) << 16);
}

__device__ __forceinline__ void gld_lds16(const ushort* g, ushort* l) {
  __builtin_amdgcn_global_load_lds(
      (const __attribute__((address_space(1))) unsigned int*)g,
      (__attribute__((address_space(3))) unsigned int*)l, 16, 0, 0);
}

// order-preserving float->u32; key = (score, ~idx) so ties pick smaller idx
__device__ __forceinline__ unsigned long long score_key(float v, int l) {
  unsigned u = __float_as_uint(v);
  unsigned k32 = (u & 0x80000000u) ? ~u : (u | 0x80000000u);
  return ((unsigned long long)k32 << 32) | (unsigned)(~l);
}

// ---------------------------------------------------------------------------
// gather last_back = sent[:, 0, 512:1024]
__global__ void k_gather_lastb(const float* __restrict__ sent, float* __restrict__ lastb) {
  int i = blockIdx.x * 256 + threadIdx.x;        // 65536 = 128*512
  int b = i >> 9, k = i & 511;
  lastb[i] = sent[(size_t)b * (Ln * D2n) + 512 + k];
}

// ---------------------------------------------------------------------------
// split fp32 -> hi/lo bf16 (used for both wd [512x1024] and sent [25600x1024])
__global__ void k_split(const float* __restrict__ W, ushort* __restrict__ hi,
                        ushort* __restrict__ lo) {
  int i = blockIdx.x * 256 + threadIdx.x;        // float4 index
  float4 v = ((const float4*)W)[i];
  ushort4 h, l;
  h.x = f2bf(v.x); l.x = f2bf(v.x - bf2f(h.x));
  h.y = f2bf(v.y); l.y = f2bf(v.y - bf2f(h.y));
  h.z = f2bf(v.z); l.z = f2bf(v.z - bf2f(h.z));
  h.w = f2bf(v.w); l.w = f2bf(v.w - bf2f(h.w));
  ((ushort4*)hi)[i] = h;
  ((ushort4*)lo)[i] = l;
}

// ---------------------------------------------------------------------------
// 32x32 tiled transpose: out[c][r] = in[r][c]; R,C multiples of 32
__global__ void k_transp(const float* __restrict__ in, float* __restrict__ out,
                         int R, int C) {
  __shared__ float t[32][33];
  const int x = threadIdx.x, y = threadIdx.y;     // 32 x 8
  const int c0 = blockIdx.x * 32, r0 = blockIdx.y * 32;
  #pragma unroll
  for (int i = 0; i < 4; ++i)
    t[y + i * 8][x] = in[(size_t)(r0 + y + i * 8) * C + c0 + x];
  __syncthreads();
  #pragma unroll
  for (int i = 0; i < 4; ++i)
    out[(size_t)(c0 + y + i * 8) * R + r0 + x] = t[x][y + i * 8];
}

// ---------------------------------------------------------------------------
// small GEMM (preamble h0 only): out[b,j] = act(bias[j] + sum_k in[b,k]*W[j,k])
template<int K, int ACT>
__launch_bounds__(256)
__global__ void k_small_gemm(const float* __restrict__ in, const float* __restrict__ W,
                             const float* __restrict__ bias, float* __restrict__ out, int J) {
  __shared__ float s[16 * K];
  const int b0 = blockIdx.y * 16;
  const int jl = threadIdx.x & 63;
  const int j  = blockIdx.x * 64 + jl;
  const int bg = (threadIdx.x >> 6) * 4;         // 0,4,8,12

  const float4* inp4 = (const float4*)(in + (size_t)b0 * K);
  float4* s4 = (float4*)s;
  for (int i = threadIdx.x; i < 4 * K; i += 256) s4[i] = inp4[i];
  __syncthreads();

  const float4* w4 = (const float4*)(W + (size_t)j * K);
  const float4* r0 = (const float4*)(s + (size_t)(bg + 0) * K);
  const float4* r1 = (const float4*)(s + (size_t)(bg + 1) * K);
  const float4* r2 = (const float4*)(s + (size_t)(bg + 2) * K);
  const float4* r3 = (const float4*)(s + (size_t)(bg + 3) * K);

  float acc0 = 0.f, acc1 = 0.f, acc2 = 0.f, acc3 = 0.f;
  #pragma unroll 4
  for (int k4 = 0; k4 < K / 4; ++k4) {
    float4 wv = w4[k4];
    float4 a;
    a = r0[k4]; acc0 += wv.x*a.x + wv.y*a.y + wv.z*a.z + wv.w*a.w;
    a = r1[k4]; acc1 += wv.x*a.x + wv.y*a.y + wv.z*a.z + wv.w*a.w;
    a = r2[k4]; acc2 += wv.x*a.x + wv.y*a.y + wv.z*a.z + wv.w*a.w;
    a = r3[k4]; acc3 += wv.x*a.x + wv.y*a.y + wv.z*a.z + wv.w*a.w;
  }
  float bb = bias[j];
  float v;
  v = acc0 + bb; if (ACT) v = tanhf(v); out[(size_t)(b0 + bg + 0) * J + j] = v;
  v = acc1 + bb; if (ACT) v = tanhf(v); out[(size_t)(b0 + bg + 1) * J + j] = v;
  v = acc2 + bb; if (ACT) v = tanhf(v); out[(size_t)(b0 + bg + 2) * J + j] = v;
  v = acc3 + bb; if (ACT) v = tanhf(v); out[(size_t)(b0 + bg + 3) * J + j] = v;
}

// ---------------------------------------------------------------------------
// d_proj = sent @ wd^T + bd via split-bf16 MFMA (unchanged from R3: 108us,
// MfmaUtil 31%, 0 conflicts, FETCH 112MB -- control group this round)
constexpr int NSTEP = Kn / 32;   // 32

__launch_bounds__(256)
__global__ void k_dproj_mfma(const ushort* __restrict__ Ahi, const ushort* __restrict__ Alo,
                             const ushort* __restrict__ Whi, const ushort* __restrict__ Wlo,
                             const float* __restrict__ bias, float* __restrict__ C) {
  __shared__ __align__(16) ushort sAh[128 * 32];
  __shared__ __align__(16) ushort sAl[128 * 32];
  __shared__ __align__(16) ushort sBh[128 * 32];
  __shared__ __align__(16) ushort sBl[128 * 32];

  const int bid = blockIdx.x;
  const int m0  = (bid % 200) * 128;
  const int n0  = (bid / 200) * 128;

  const int tid  = threadIdx.x;
  const int wave = tid >> 6, lane = tid & 63;
  const int wy = (wave >> 1) * 64, wx = (wave & 1) * 64;
  const int lm = lane & 15, lq = lane >> 4;

  const int fs = (lq ^ ((lm >> 1) & 3)) * 8;     // swizzled 16B slot

  const int S0 = (wave * 2 + 0) * 64 + lane;
  const int S1 = (wave * 2 + 1) * 64 + lane;
  const int r0 = S0 >> 2, r1 = S1 >> 2;
  const int c0 = ((S0 & 3) ^ ((r0 >> 1) & 3)) * 8;
  const int c1 = ((S1 & 3) ^ ((r1 >> 1) & 3)) * 8;
  const ushort* pAh0 = Ahi + (size_t)(m0 + r0) * Kn + c0;
  const ushort* pAh1 = Ahi + (size_t)(m0 + r1) * Kn + c1;
  const ushort* pAl0 = Alo + (size_t)(m0 + r0) * Kn + c0;
  const ushort* pAl1 = Alo + (size_t)(m0 + r1) * Kn + c1;
  const ushort* pBh0 = Whi + (size_t)(n0 + r0) * Kn + c0;
  const ushort* pBh1 = Whi + (size_t)(n0 + r1) * Kn + c1;
  const ushort* pBl0 = Wlo + (size_t)(n0 + r0) * Kn + c0;
  const ushort* pBl1 = Wlo + (size_t)(n0 + r1) * Kn + c1;
  ushort* dA0 = &sAh[S0 * 8]; ushort* dA1 = &sAh[S1 * 8];
  ushort* dL0 = &sAl[S0 * 8]; ushort* dL1 = &sAl[S1 * 8];
  ushort* dB0 = &sBh[S0 * 8]; ushort* dB1 = &sBh[S1 * 8];
  ushort* dC0 = &sBl[S0 * 8]; ushort* dC1 = &sBl[S1 * 8];

  f32x4 acc[4][4] = {};

  for (int ks = 0; ks < NSTEP; ++ks) {
    const int ko = ks * 32;
    gld_lds16(pAh0 + ko, dA0); gld_lds16(pAh1 + ko, dA1);
    gld_lds16(pAl0 + ko, dL0); gld_lds16(pAl1 + ko, dL1);
    gld_lds16(pBh0 + ko, dB0); gld_lds16(pBh1 + ko, dB1);
    gld_lds16(pBl0 + ko, dC0); gld_lds16(pBl1 + ko, dC1);
    __syncthreads();

    bf16x8 ah[4], al[4], bh[4], bl[4];
    #pragma unroll
    for (int mi = 0; mi < 4; ++mi) {
      const int o = (wy + mi * 16 + lm) * 32 + fs;
      ah[mi] = *(const bf16x8*)&sAh[o];
      al[mi] = *(const bf16x8*)&sAl[o];
    }
    #pragma unroll
    for (int ni = 0; ni < 4; ++ni) {
      const int o = (wx + ni * 16 + lm) * 32 + fs;
      bh[ni] = *(const bf16x8*)&sBh[o];
      bl[ni] = *(const bf16x8*)&sBl[o];
    }
    #pragma unroll
    for (int mi = 0; mi < 4; ++mi)
      #pragma unroll
      for (int ni = 0; ni < 4; ++ni) {
        acc[mi][ni] = __builtin_amdgcn_mfma_f32_16x16x32_bf16(ah[mi], bh[ni], acc[mi][ni], 0, 0, 0);
        acc[mi][ni] = __builtin_amdgcn_mfma_f32_16x16x32_bf16(ah[mi], bl[ni], acc[mi][ni], 0, 0, 0);
        acc[mi][ni] = __builtin_amdgcn_mfma_f32_16x16x32_bf16(al[mi], bh[ni], acc[mi][ni], 0, 0, 0);
      }
    __syncthreads();
  }

  #pragma unroll
  for (int ni = 0; ni < 4; ++ni) {
    int col = n0 + wx + ni * 16 + lm;
    float bb = bias[col];
    #pragma unroll
    for (int mi = 0; mi < 4; ++mi) {
      int rbase = m0 + wy + mi * 16 + lq * 4;
      #pragma unroll
      for (int r = 0; r < 4; ++r)
        C[(size_t)(rbase + r) * Nn + col] = acc[mi][ni][r] + bb;
    }
  }
}

// ---------------------------------------------------------------------------
// fused GRU step: h_new = GRU(s_row, h_old) using TRANSPOSED weights
// (coalesced j-major reads). Grid 256 = 8 j-tiles x 32 b-tiles; block 512 =
// 64 j-lanes x {4 b} x {2 K-halves}; LDS combine of K-half partials.
__launch_bounds__(512)
__global__ void k_gru(const float* __restrict__ s_row, const float* __restrict__ h_old,
                      const float* __restrict__ wihT, const float* __restrict__ whhT,
                      const float* __restrict__ b_ih, const float* __restrict__ b_hh,
                      float* __restrict__ h_new) {
  __shared__ __align__(16) float sS[4][1024];
  __shared__ __align__(16) float sH[4][512];
  __shared__ float sP[256][6];

  const int tid  = threadIdx.x;
  const int lane = tid & 63;
  const int wave = tid >> 6;              // 0..7
  const int b_loc = wave & 3, kh = wave >> 2;
  const int jt = blockIdx.x & 7, bt = blockIdx.x >> 3;   // 8 x 32
  const int j  = jt * 64 + lane;

  {
    const float4* src = (const float4*)(s_row + (size_t)bt * 4 * 1024);
    float4* dst = (float4*)&sS[0][0];
    dst[tid] = src[tid];
    dst[tid + 512] = src[tid + 512];
    ((float4*)&sH[0][0])[tid] = ((const float4*)(h_old + (size_t)bt * 4 * 512))[tid];
  }
  __syncthreads();

  float xr = 0, xz = 0, xn = 0, hr = 0, hz = 0, hn = 0;
  {
    const float* w = wihT + (size_t)(kh * 512) * G3n + j;
    const float4* sv4 = (const float4*)&sS[b_loc][kh * 512];
    #pragma unroll 2
    for (int k4 = 0; k4 < 128; ++k4) {
      float4 sv = sv4[k4];
      xr += w[0] * sv.x; xz += w[512] * sv.x; xn += w[1024] * sv.x; w += G3n;
      xr += w[0] * sv.y; xz += w[512] * sv.y; xn += w[1024] * sv.y; w += G3n;
      xr += w[0] * sv.z; xz += w[512] * sv.z; xn += w[1024] * sv.z; w += G3n;
      xr += w[0] * sv.w; xz += w[512] * sv.w; xn += w[1024] * sv.w; w += G3n;
    }
  }
  {
    const float* w = whhT + (size_t)(kh * 256) * G3n + j;
    const float4* hv4 = (const float4*)&sH[b_loc][kh * 256];
    #pragma unroll 2
    for (int k4 = 0; k4 < 64; ++k4) {
      float4 hv = hv4[k4];
      hr += w[0] * hv.x; hz += w[512] * hv.x; hn += w[1024] * hv.x; w += G3n;
      hr += w[0] * hv.y; hz += w[512] * hv.y; hn += w[1024] * hv.y; w += G3n;
      hr += w[0] * hv.z; hz += w[512] * hv.z; hn += w[1024] * hv.z; w += G3n;
      hr += w[0] * hv.w; hz += w[512] * hv.w; hn += w[1024] * hv.w; w += G3n;
    }
  }
  const int pidx = b_loc * 64 + lane;
  if (kh) {
    sP[pidx][0] = xr; sP[pidx][1] = xz; sP[pidx][2] = xn;
    sP[pidx][3] = hr; sP[pidx][4] = hz; sP[pidx][5] = hn;
  }
  __syncthreads();
  if (!kh) {
    xr += sP[pidx][0]; xz += sP[pidx][1]; xn += sP[pidx][2];
    hr += sP[pidx][3]; hz += sP[pidx][4]; hn += sP[pidx][5];
    xr += b_ih[j];        hr += b_hh[j];
    xz += b_ih[512 + j];  hz += b_hh[512 + j];
    xn += b_ih[1024 + j]; hn += b_hh[1024 + j];
    float r = 1.f / (1.f + expf(-(xr + hr)));
    float z = 1.f / (1.f + expf(-(xz + hz)));
    float n = tanhf(xn + r * hn);
    const int b = bt * 4 + b_loc;
    float hold = sH[b_loc][j];
    h_new[(size_t)b * 512 + j] = (1.f - z) * n + z * hold;
  }
}

// ---------------------------------------------------------------------------
// q = h @ wq^T + bq with transposed wq (coalesced). Grid 256 = 8 jt x 32 bt.
__launch_bounds__(256)
__global__ void k_qT(const float* __restrict__ h, const float* __restrict__ wqT,
                     const float* __restrict__ bq, float* __restrict__ q) {
  __shared__ __align__(16) float sH[4][512];
  const int tid = threadIdx.x, lane = tid & 63, bw = tid >> 6;  // 4 waves = 4 b
  const int jt = blockIdx.x & 7, bt = blockIdx.x >> 3;
  const int j = jt * 64 + lane;
  {
    float4* dst = (float4*)&sH[0][0];
    const float4* src = (const float4*)(h + (size_t)bt * 2048);
    dst[tid] = src[tid];
    dst[tid + 256] = src[tid + 256];
  }
  __syncthreads();
  float acc = 0.f;
  const float* w = wqT + j;
  const float4* hv4 = (const float4*)&sH[bw][0];
  #pragma unroll 4
  for (int k4 = 0; k4 < 128; ++k4) {
    float4 hv = hv4[k4];
    acc += w[0] * hv.x; w += 512;
    acc += w[0] * hv.y; w += 512;
    acc += w[0] * hv.z; w += 512;
    acc += w[0] * hv.w; w += 512;
  }
  const int b = bt * 4 + bw;
  q[(size_t)b * 512 + j] = acc + bq[j];
}

// ---------------------------------------------------------------------------
// score[b,l] = sum_a tanh(q[b,a] + dproj[b*L+l,a]) * ws[a] + bs; mask;
// write outScores; fold argmax in via packed atomicMax (first-idx tiebreak).
__launch_bounds__(256)
__global__ void k_score(const float* __restrict__ dproj, const float* __restrict__ q,
                        const float* __restrict__ wsv, const float* __restrict__ bsv,
                        const int* __restrict__ mask, unsigned long long* __restrict__ packed,
                        float* __restrict__ outScores, int t) {
  int w = blockIdx.x * 4 + (threadIdx.x >> 6);   // 0..25599
  int lane = threadIdx.x & 63;
  int b = w / Ln, l = w % Ln;
  const float4* dp4 = (const float4*)(dproj + (size_t)w * Nn);
  const float4* q4  = (const float4*)(q + (size_t)b * Nn);
  const float4* ws4 = (const float4*)wsv;

  float sum = 0.f;
  #pragma unroll
  for (int i = 0; i < 2; ++i) {
    int idx = lane + i * 64;                     // 128 float4 per row
    float4 d = dp4[idx], qq = q4[idx], wv = ws4[idx];
    sum += tanhf(qq.x + d.x) * wv.x + tanhf(qq.y + d.y) * wv.y
         + tanhf(qq.z + d.z) * wv.z + tanhf(qq.w + d.w) * wv.w;
  }
  #pragma unroll
  for (int off = 32; off > 0; off >>= 1) sum += __shfl_xor(sum, off, 64);

  if (lane == 0) {
    float v = sum + bsv[0];
    if (mask[w]) v = -1000000.0f;
    outScores[(size_t)b * (Tn * Ln) + t * Ln + l] = v;
    atomicMax(&packed[b], score_key(v, l));
  }
}

// ---------------------------------------------------------------------------
// decode winner, gather selected row, update mask, reset packed
__launch_bounds__(256)
__global__ void k_argmax(unsigned long long* __restrict__ packed,
                         const float* __restrict__ sent,
                         float* __restrict__ s_row, int* __restrict__ mask,
                         float* __restrict__ outSel, int t) {
  int b = blockIdx.x;
  __shared__ int s_idx;
  int tid = threadIdx.x;
  if (tid == 0) {
    unsigned long long key = packed[b];
    s_idx = (int)(~(unsigned)(key & 0xFFFFFFFFull));
  }
  __syncthreads();
  int idx = s_idx;
  const float* src = sent + ((size_t)b * Ln + idx) * D2n;
  float* dstp = s_row + (size_t)b * D2n;
  int k = tid * 4;                               // 256 threads x 4 = 1024
  *(float4*)(dstp + k) = *(const float4*)(src + k);
  if (tid == 0) {
    mask[b * Ln + idx] = 1;
    outSel[(size_t)b * Tn + t] = (float)idx;
    packed[b] = 0ull;                            // ready for next t
  }
}

// ---------------------------------------------------------------------------
extern "C" void kernel_launch(void* const* d_in, const int* in_sizes, int n_in,
                              void* d_out, int out_size, void* d_ws, size_t ws_size,
                              hipStream_t stream) {
  const float* sent = (const float*)d_in[0];
  const float* h0_w = (const float*)d_in[1];
  const float* h0_b = (const float*)d_in[2];
  const float* w_ih = (const float*)d_in[3];
  const float* w_hh = (const float*)d_in[4];
  const float* b_ih = (const float*)d_in[5];
  const float* b_hh = (const float*)d_in[6];
  const float* wq   = (const float*)d_in[7];
  const float* bq   = (const float*)d_in[8];
  const float* wd   = (const float*)d_in[9];
  const float* bd   = (const float*)d_in[10];
  const float* wsv  = (const float*)d_in[11];
  const float* bsv  = (const float*)d_in[12];

  float* wsf     = (float*)d_ws;
  float* d_proj  = wsf;                       // 25600*512 = 13107200
  float* s_row   = d_proj + 13107200;         // 128*1024
  float* hA      = s_row + 131072;            // 128*512
  float* hB      = hA + 65536;                // 128*512
  float* lastb   = hB + 65536;                // 128*512
  float* q       = lastb + 65536;             // 128*512
  float* wihT    = q + 65536;                 // 1024*1536
  float* whhT    = wihT + 1572864;            // 512*1536
  float* wqT     = whhT + 786432;             // 512*512
  int*   mask    = (int*)(wqT + 262144);      // 128*200 ints
  unsigned long long* packed = (unsigned long long*)(mask + 25600);  // 128 u64
  ushort* Whi    = (ushort*)(packed + 128);   // 512*1024 shorts
  ushort* Wlo    = Whi + 524288;              // 512*1024 shorts
  ushort* Ahi    = Wlo + 524288;              // 25600*1024 shorts
  ushort* Alo    = Ahi + 26214400;            // 25600*1024 shorts

  float* outScores = (float*)d_out;                       // (B, T, L) fp32
  float* outSel    = outScores + (size_t)Bn * Tn * Ln;    // (B, T) fp32

  hipMemsetAsync(s_row, 0, 131072 * sizeof(float), stream);       // s_prev(t=0) = 0
  hipMemsetAsync(mask, 0, 25600 * sizeof(int), stream);
  hipMemsetAsync(packed, 0, 128 * sizeof(unsigned long long), stream);

  k_gather_lastb<<<256, 256, 0, stream>>>(sent, lastb);
  k_small_gemm<512, 1><<<dim3(8, 8), 256, 0, stream>>>(lastb, h0_w, h0_b, hA, 512);
  k_transp<<<dim3(32, 48), dim3(32, 8), 0, stream>>>(w_ih, wihT, 1536, 1024);
  k_transp<<<dim3(16, 48), dim3(32, 8), 0, stream>>>(w_hh, whhT, 1536, 512);
  k_transp<<<dim3(16, 16), dim3(32, 8), 0, stream>>>(wq, wqT, 512, 512);
  k_split<<<512, 256, 0, stream>>>(wd, Whi, Wlo);         // 512*1024/4 float4
  k_split<<<25600, 256, 0, stream>>>(sent, Ahi, Alo);     // 25600*1024/4 float4
  k_dproj_mfma<<<800, 256, 0, stream>>>(Ahi, Alo, Whi, Wlo, bd, d_proj);

  float* hc = hA;
  float* hn = hB;
  for (int t = 0; t < Tn; ++t) {
    k_gru<<<256, 512, 0, stream>>>(s_row, hc, wihT, whhT, b_ih, b_hh, hn);
    k_qT<<<256, 256, 0, stream>>>(hn, wqT, bq, q);
    k_score<<<6400, 256, 0, stream>>>(d_proj, q, wsv, bsv, mask, packed, outScores, t);
    k_argmax<<<128, 256, 0, stream>>>(packed, sent, s_row, mask, outSel, t);
    float* tmp = hc; hc = hn; hn = tmp;
  }
}